// Round 8
// baseline (298.031 us; speedup 1.0000x reference)
//
#include <hip/hip_runtime.h>

typedef unsigned char u8;
typedef float f32x4 __attribute__((ext_vector_type(4)));

#define P_OUT 29791      // 31^3
#define NCH   512

// ---- pack 4 fp32 -> 4 fp8 e4m3 (RNE, OCP) ----
__device__ __forceinline__ unsigned pk4_fp8(float a, float b, float c, float d) {
  int v = __builtin_amdgcn_cvt_pk_fp8_f32(a, b, 0, false);   // low word
  v = __builtin_amdgcn_cvt_pk_fp8_f32(c, d, v, true);        // high word
  return (unsigned)v;
}

// ---- w-prep: 512 rows, 16 rows/block, 32 blocks ----
__global__ void wprep_kernel(const float* __restrict__ w,
                             u8* __restrict__ wb, float* __restrict__ wsq) {
  const int tid = threadIdx.x;
  const int g = blockIdx.x * 16 + (tid >> 4);  // 0..511
  const int c = tid & 15;
  const float4* wr = (const float4*)(w + g * 128 + c * 8);
  float4 f0 = wr[0], f1 = wr[1];
  float s = f0.x*f0.x + f0.y*f0.y + f0.z*f0.z + f0.w*f0.w
          + f1.x*f1.x + f1.y*f1.y + f1.z*f1.z + f1.w*f1.w;
#pragma unroll
  for (int m = 1; m < 16; m <<= 1) s += __shfl_xor(s, m, 64);
  uint2 pk;
  pk.x = pk4_fp8(f0.x, f0.y, f0.z, f0.w);
  pk.y = pk4_fp8(f1.x, f1.y, f1.z, f1.w);
  *(uint2*)(wb + g * 128 + c * 8) = pk;
  if (c == 0) wsq[g] = s;
}

// async global->LDS, 16 B per lane, lands at ldsbase + lane*16
#define GLDS(g, l) __builtin_amdgcn_global_load_lds(                         \
    (const __attribute__((address_space(1))) unsigned int*)(g),              \
    (__attribute__((address_space(3))) unsigned int*)(l), 16, 0, 0)

// ---- Fused unfold + GEMM + epilogue, WIDE-P version ----
// Tile = (nb, ct, d, pq): 128 ch x 248 p (8 h-rows x 31 w; pq=3 -> 217).
// p is LINEAR in the output -> each block writes a 992 B (868 B) CONTIGUOUS
// strip per ch row (2x the r5 strip): DRAM row-activation amortization is
// the target (r3 measured 2.0 TB/s effective on 496 B strips).
// 512 threads = 8 waves (2 ch-halves x 4 p-quarters), per-wave acc 4x4 --
// identical fragment/index math to the verified r5/r7 kernels.
// Xs slab [16c][2kd][9hq][32w] fp32 (36.9 KB) staged once via GLDS;
// B-fragments packed once into 32 VGPRs (r7-verbatim, strides kd=288,
// kh=32, kw=1). Ws staging/swizzle + MFMA + epilogue formula verbatim.
// XCD-chunked bijective decode: 1984 = 8*248, pq fastest -> same-XCD
// blocks write contiguous 961-p planes (L2 write locality).
__global__ __launch_bounds__(512)
void gauss_fused_kernel(const float* __restrict__ x,
                        const u8* __restrict__ wb,
                        const float* __restrict__ wsq,
                        float* __restrict__ out) {
  __shared__ __align__(16) u8 Ws[128 * 128];     // w tile [ch][k], 16 KB
  __shared__ __align__(16) float Xs[9216];       // x slab, 36,864 B

  const int bid = blockIdx.x;
  const int tile = (bid & 7) * 248 + (bid >> 3);   // bijective XCD chunking
  const unsigned pq = (unsigned)tile & 3u;         // 4 p-quarters, fastest
  const unsigned t2 = (unsigned)tile >> 2;         // 0..495
  const unsigned d  = t2 % 31u;                    // 31 d values
  const unsigned t3 = t2 / 31u;                    // 0..15
  const unsigned ct = t3 & 3u;                     // 4 ch tiles
  const unsigned nb = t3 >> 2;                     // 4 batches

  const int h0 = pq * 8;
  const int nrows = (pq < 3) ? 248 : 217;          // real p-rows in tile
  const int tp0 = d * 961 + pq * 248;              // tile's base p
  const int c0 = ct * 128;

  const int tid = threadIdx.x;
  const int wid = tid >> 6;      // 0..7
  const int lane = tid & 63;
  const int quad = lane >> 4;
  const int col = lane & 15;
  const int wch = wid & 1;       // wave ch-half (2 x 64 ch)
  const int wp = wid >> 1;       // wave p-quarter (4 x 64 p)

  // ---- stage W tile: 1024 swizzled chunks, 2 rounds of 512 ----
#pragma unroll
  for (int t = 0; t < 2; ++t) {
    const int Lb = (wid * 2 + t) * 64;
    const int L = Lb + lane;
    const int row = L >> 3;
    const int jc = (L & 7) ^ (row & 7);
    GLDS(wb + (size_t)(c0 + row) * 128 + jc * 16, &Ws[Lb * 16]);
  }

  // ---- stage x slab [16c][2kd][9hq][32w]: 288 rows = 2304 chunks ----
  // 4 full rounds of 512 + partial round (first 4 waves)
#pragma unroll
  for (int t = 0; t < 5; ++t) {
    if (t < 4 || wid < 4) {
      const int Lb = t * 512 + wid * 64;
      const int L = Lb + lane;
      const int row = L >> 3;               // 0..287
      const int jc = L & 7;
      const unsigned c = (unsigned)row / 18u;
      const unsigned rr = (unsigned)row - c * 18u;
      const unsigned kd = rr / 9u;
      const unsigned hq = rr - kd * 9u;
      const int hg = h0 + (int)hq;
      const int hcl = (hg < 31) ? hg : 31;  // pq=3 tail slot, unused
      GLDS(x + (((size_t)(nb * 16 + c)) << 15) + (d + kd) * 1024 + hcl * 32 + jc * 4,
           &Xs[Lb * 4]);
    }
  }

  // ---- per-lane p-row decode (hides under GLDS flight) ----
  int rb[4];
  int xoff[4];
#pragma unroll
  for (int j = 0; j < 4; ++j) {
    rb[j] = wp * 64 + j * 16 + col;
    const unsigned rc = (unsigned)((rb[j] < nrows) ? rb[j] : (nrows - 1));
    const unsigned hh = rc / 31u;           // local h row (0..7)
    const unsigned wv = rc - hh * 31u;
    xoff[j] = (int)(hh * 32 + wv);
  }

  __syncthreads();   // drains all GLDS

  // ---- build B fragments ONCE into registers (r7-verbatim pack) ----
  long long B[4][4];
  float sq[4] = {0.f, 0.f, 0.f, 0.f};
#pragma unroll
  for (int ks = 0; ks < 4; ++ks) {
    const int cc = ks * 4 + quad;           // channel for this lane's k-chunk
    const float* xb = &Xs[cc * 576];        // [kd][hq][32] view
#pragma unroll
    for (int j = 0; j < 4; ++j) {
      const float* pB = xb + xoff[j];
      // k-elem order = (kd,kh,kw): strides kd=288, kh=32, kw=1 floats
      const float v0 = pB[0],   v1 = pB[1],   v2 = pB[32],  v3 = pB[33];
      const float v4 = pB[288], v5 = pB[289], v6 = pB[320], v7 = pB[321];
      sq[j] += v0*v0 + v1*v1 + v2*v2 + v3*v3 + v4*v4 + v5*v5 + v6*v6 + v7*v7;
      const unsigned lo = pk4_fp8(v0, v1, v2, v3);
      const unsigned hi = pk4_fp8(v4, v5, v6, v7);
      B[ks][j] = (long long)(((unsigned long long)hi << 32) | lo);
    }
  }
  // full ysq per row: reduce partials across the 4 quads
#pragma unroll
  for (int j = 0; j < 4; ++j) {
    sq[j] += __shfl_xor(sq[j], 16, 64);
    sq[j] += __shfl_xor(sq[j], 32, 64);
  }

  // ---- MFMA (A via r5-verbatim swizzled b64 reads, B from registers) ----
  f32x4 acc[4][4];
#pragma unroll
  for (int i = 0; i < 4; ++i)
#pragma unroll
    for (int j = 0; j < 4; ++j) acc[i][j] = (f32x4){0.f, 0.f, 0.f, 0.f};

  const int c16b = quad >> 1;
  const int hoff = (quad & 1) * 8;
#pragma unroll
  for (int ks = 0; ks < 4; ++ks) {
    long long a[4];
#pragma unroll
    for (int i = 0; i < 4; ++i) {
      const int rowA = wch * 64 + i * 16 + col;
      const int pa = (ks * 2 + c16b) ^ (rowA & 7);
      a[i] = *(const long long*)&Ws[rowA * 128 + pa * 16 + hoff];
    }
#pragma unroll
    for (int i = 0; i < 4; ++i)
#pragma unroll
      for (int j = 0; j < 4; ++j)
        acc[i][j] = __builtin_amdgcn_mfma_f32_16x16x32_fp8_fp8(a[i], B[ks][j],
                                                               acc[i][j], 0, 0, 0);
  }
  // no trailing barrier: stores below are fire-and-forget to kernel end

  // ---- epilogue: out = exp(2*cross - ysq - wsq), fire-and-forget ----
#pragma unroll
  for (int i = 0; i < 4; ++i) {
#pragma unroll
    for (int r = 0; r < 4; ++r) {
      const int ch = c0 + wch * 64 + i * 16 + quad * 4 + r;
      const float wsv = wsq[ch];
      float* ob = out + ((size_t)(nb * NCH + ch)) * P_OUT;
#pragma unroll
      for (int j = 0; j < 4; ++j)
        if (rb[j] < nrows)
          ob[tp0 + rb[j]] = __expf(2.f * acc[i][j][r] - sq[j] - wsv);
    }
  }
}

extern "C" void kernel_launch(void* const* d_in, const int* in_sizes, int n_in,
                              void* d_out, int out_size, void* d_ws, size_t ws_size,
                              hipStream_t stream) {
  const float* x = (const float*)d_in[0];
  const float* w = (const float*)d_in[1];
  float* out = (float*)d_out;
  char* ws = (char*)d_ws;
  // workspace: wb 512*128 fp8 = 65,536 B ; wsq 512*4 = 2,048 B
  u8* wb     = (u8*)ws;
  float* wsq = (float*)(ws + 65536);

  wprep_kernel<<<32, 256, 0, stream>>>(w, wb, wsq);
  gauss_fused_kernel<<<1984, 512, 0, stream>>>(x, wb, wsq, out);
}

// Round 9
// 274.763 us; speedup vs baseline: 1.0847x; 1.0847x over previous
//
#include <hip/hip_runtime.h>

typedef unsigned char u8;
typedef float f32x4 __attribute__((ext_vector_type(4)));

#define P_OUT 29791      // 31^3
#define NCH   512

// ---- pack 4 fp32 -> 4 fp8 e4m3 (RNE, OCP) ----
__device__ __forceinline__ unsigned pk4_fp8(float a, float b, float c, float d) {
  int v = __builtin_amdgcn_cvt_pk_fp8_f32(a, b, 0, false);   // low word
  v = __builtin_amdgcn_cvt_pk_fp8_f32(c, d, v, true);        // high word
  return (unsigned)v;
}

// ---- w-prep: 512 rows, 16 rows/block, 32 blocks ----
__global__ void wprep_kernel(const float* __restrict__ w,
                             u8* __restrict__ wb, float* __restrict__ wsq) {
  const int tid = threadIdx.x;
  const int g = blockIdx.x * 16 + (tid >> 4);  // 0..511
  const int c = tid & 15;
  const float4* wr = (const float4*)(w + g * 128 + c * 8);
  float4 f0 = wr[0], f1 = wr[1];
  float s = f0.x*f0.x + f0.y*f0.y + f0.z*f0.z + f0.w*f0.w
          + f1.x*f1.x + f1.y*f1.y + f1.z*f1.z + f1.w*f1.w;
#pragma unroll
  for (int m = 1; m < 16; m <<= 1) s += __shfl_xor(s, m, 64);
  uint2 pk;
  pk.x = pk4_fp8(f0.x, f0.y, f0.z, f0.w);
  pk.y = pk4_fp8(f1.x, f1.y, f1.z, f1.w);
  *(uint2*)(wb + g * 128 + c * 8) = pk;
  if (c == 0) wsq[g] = s;
}

// async global->LDS, 16 B per lane, lands at ldsbase + lane*16
#define GLDS(g, l) __builtin_amdgcn_global_load_lds(                         \
    (const __attribute__((address_space(1))) unsigned int*)(g),              \
    (__attribute__((address_space(3))) unsigned int*)(l), 16, 0, 0)

// ---- Fused unfold + GEMM + epilogue, HB-LOOP version ----
// Strip-length A/B vs the r7 ct-loop: SAME 992-block grid, SAME 256-thread
// 4-wave shape, SAME 4-iteration inner loop + 2 barriers/iter -- but the
// loop now walks hb (p-extent) at FIXED ct, so each block writes a
// 1,922 B CONTIGUOUS ascending run per ch row (4 x 496 B) instead of four
// scattered 496 B strips. Target: DRAM row-locality of the write stream
// (r3 measured 2.0 TB/s effective on 0.5 KB strips; theory: open strips
// >> HBM banks -> row-miss bound).
// Block = (nb, ct, d, hh): hh picks h rows [hh*16, hh*16+16) (hh=1: 15).
// Iter it: 124-row p-subtile at h0 = hh*16+it*4 (hh=1,it=3: 93 rows).
// Xs slab [16c][2kd][5hq][32w] fp32 (20 KB) re-staged per iter (1-row halo
// overlap); B-fragments packed per iter into 32 VGPRs (r5-verbatim pack:
// k = ks*32+quad*8+j, j=(kd,kh,kw) strides 160/32/1, c = ks*4+quad).
// Ws staged ONCE (ct fixed). MFMA + A-reads + epilogue r5-verbatim.
// Schedule/iter: pack -> bar -> GLDS(next slab) -> MFMA -> stores -> bar;
// GLDS flight hides under MFMA+epilogue; stores drain at L2-ack cost only.
// XCD-chunked bijective decode: 992 = 8*124; hh fastest, then d -> same-XCD
// blocks cover adjacent p-ranges of the same (nb,ct) rows.
__global__ __launch_bounds__(256, 2)
void gauss_fused_kernel(const float* __restrict__ x,
                        const u8* __restrict__ wb,
                        const float* __restrict__ wsq,
                        float* __restrict__ out) {
  __shared__ __align__(16) u8 Ws[128 * 128];   // w tile [ch][k], 16 KB
  __shared__ __align__(16) float Xs[5120];     // x slab, 20 KB

  const int bid = blockIdx.x;
  const int tile = (bid & 7) * 124 + (bid >> 3);   // bijective XCD chunking
  const unsigned hh = (unsigned)tile & 1u;         // h-half, fastest
  const unsigned t2 = (unsigned)tile >> 1;
  const unsigned d  = t2 % 31u;                    // 31 d values
  const unsigned t3 = t2 / 31u;
  const unsigned ct = t3 & 3u;                     // 4 ch tiles
  const unsigned nb = t3 >> 2;                     // 4 batches
  const int c0 = ct * 128;

  const int tid = threadIdx.x;
  const int wid = tid >> 6;
  const int lane = tid & 63;
  const int quad = lane >> 4;
  const int col = lane & 15;
  const int wch = wid & 1;   // wave ch-half
  const int wp = wid >> 1;   // wave p-half

  // ---- stage W tile ONCE: 1024 swizzled chunks (r5 verbatim) ----
#pragma unroll
  for (int t = 0; t < 4; ++t) {
    const int Lb = (wid * 4 + t) * 64;
    const int L = Lb + lane;
    const int row = L >> 3;
    const int jc = (L & 7) ^ (row & 7);
    GLDS(wb + (size_t)(c0 + row) * 128 + jc * 16, &Ws[Lb * 16]);
  }

  // ---- stage Xs slab for iteration 0 (h0 = hh*16) ----
  {
    const int h0 = (int)hh * 16;
#pragma unroll
    for (int t = 0; t < 5; ++t) {
      const int Lb = t * 256 + wid * 64;
      const int L = Lb + lane;
      const int row = L >> 3;                // 0..159
      const int jc = L & 7;
      const unsigned c = (unsigned)row / 10u;
      const unsigned rr = (unsigned)row - c * 10u;
      const unsigned kd = rr / 5u;
      const unsigned hq = rr - kd * 5u;
      const int hg = h0 + (int)hq;
      const int hcl = (hg < 31) ? hg : 31;
      GLDS(x + (((size_t)(nb * 16 + c)) << 15) + (d + kd) * 1024 + hcl * 32 + jc * 4,
           &Xs[Lb * 4]);
    }
  }

  const int c16b = quad >> 1;
  const int hoff = (quad & 1) * 8;

  __syncthreads();   // drains Ws + Xs(it=0)

  for (int it = 0; it < 4; ++it) {
    const int h0 = (int)hh * 16 + it * 4;
    const int nrows = (hh == 1 && it == 3) ? 93 : 124;
    const int tp0 = (int)d * 961 + h0 * 31;

    // ---- per-lane p-row decode for this subtile ----
    int rb[4];
    int xoff[4];
#pragma unroll
    for (int j = 0; j < 4; ++j) {
      rb[j] = wp * 64 + j * 16 + col;
      const unsigned rc = (unsigned)((rb[j] < nrows) ? rb[j] : (nrows - 1));
      const unsigned hl = rc / 31u;          // local h row (0..3)
      const unsigned wv = rc - hl * 31u;
      xoff[j] = (int)(hl * 32 + wv);
    }

    // ---- pack B fragments into registers (r5-verbatim) ----
    long long B[4][4];
    float sq[4] = {0.f, 0.f, 0.f, 0.f};
#pragma unroll
    for (int ks = 0; ks < 4; ++ks) {
      const int cc = ks * 4 + quad;          // channel for this lane's k-chunk
      const float* xb = &Xs[cc * 320];       // [kd][hq][32] view
#pragma unroll
      for (int j = 0; j < 4; ++j) {
        const float* pB = xb + xoff[j];
        // k-elem order = (kd,kh,kw): strides kd=160, kh=32, kw=1 floats
        const float v0 = pB[0],   v1 = pB[1],   v2 = pB[32],  v3 = pB[33];
        const float v4 = pB[160], v5 = pB[161], v6 = pB[192], v7 = pB[193];
        sq[j] += v0*v0 + v1*v1 + v2*v2 + v3*v3 + v4*v4 + v5*v5 + v6*v6 + v7*v7;
        const unsigned lo = pk4_fp8(v0, v1, v2, v3);
        const unsigned hi = pk4_fp8(v4, v5, v6, v7);
        B[ks][j] = (long long)(((unsigned long long)hi << 32) | lo);
      }
    }
#pragma unroll
    for (int j = 0; j < 4; ++j) {
      sq[j] += __shfl_xor(sq[j], 16, 64);
      sq[j] += __shfl_xor(sq[j], 32, 64);
    }

    __syncthreads();   // all lanes done reading Xs -> safe to overwrite

    // ---- issue GLDS for next subtile; flight hides under MFMA+stores ----
    if (it < 3) {
      const int hn = h0 + 4;
#pragma unroll
      for (int t = 0; t < 5; ++t) {
        const int Lb = t * 256 + wid * 64;
        const int L = Lb + lane;
        const int row = L >> 3;
        const int jc = L & 7;
        const unsigned c = (unsigned)row / 10u;
        const unsigned rr = (unsigned)row - c * 10u;
        const unsigned kd = rr / 5u;
        const unsigned hq = rr - kd * 5u;
        const int hg = hn + (int)hq;
        const int hcl = (hg < 31) ? hg : 31;
        GLDS(x + (((size_t)(nb * 16 + c)) << 15) + (d + kd) * 1024 + hcl * 32 + jc * 4,
             &Xs[Lb * 4]);
      }
    }

    // ---- MFMA (A via r5-verbatim swizzled b64 reads from Ws) ----
    f32x4 acc[4][4];
#pragma unroll
    for (int i = 0; i < 4; ++i)
#pragma unroll
      for (int j = 0; j < 4; ++j) acc[i][j] = (f32x4){0.f, 0.f, 0.f, 0.f};

#pragma unroll
    for (int ks = 0; ks < 4; ++ks) {
      long long a[4];
#pragma unroll
      for (int i = 0; i < 4; ++i) {
        const int rowA = wch * 64 + i * 16 + col;
        const int pa = (ks * 2 + c16b) ^ (rowA & 7);
        a[i] = *(const long long*)&Ws[rowA * 128 + pa * 16 + hoff];
      }
#pragma unroll
      for (int i = 0; i < 4; ++i)
#pragma unroll
        for (int j = 0; j < 4; ++j)
          acc[i][j] = __builtin_amdgcn_mfma_f32_16x16x32_fp8_fp8(a[i], B[ks][j],
                                                                 acc[i][j], 0, 0, 0);
    }

    // ---- epilogue: out = exp(2*cross - ysq - wsq), fire-and-forget ----
#pragma unroll
    for (int i = 0; i < 4; ++i) {
#pragma unroll
      for (int r = 0; r < 4; ++r) {
        const int ch = c0 + wch * 64 + i * 16 + quad * 4 + r;
        const float wsv = wsq[ch];
        float* ob = out + ((size_t)(nb * NCH + ch)) * P_OUT;
#pragma unroll
        for (int j = 0; j < 4; ++j)
          if (rb[j] < nrows)
            ob[tp0 + rb[j]] = __expf(2.f * acc[i][j][r] - sq[j] - wsv);
      }
    }

    if (it < 3) __syncthreads();   // Xs(it+1) landed; stores ack at L2
  }
}

extern "C" void kernel_launch(void* const* d_in, const int* in_sizes, int n_in,
                              void* d_out, int out_size, void* d_ws, size_t ws_size,
                              hipStream_t stream) {
  const float* x = (const float*)d_in[0];
  const float* w = (const float*)d_in[1];
  float* out = (float*)d_out;
  char* ws = (char*)d_ws;
  // workspace: wb 512*128 fp8 = 65,536 B ; wsq 512*4 = 2,048 B
  u8* wb     = (u8*)ws;
  float* wsq = (float*)(ws + 65536);

  wprep_kernel<<<32, 256, 0, stream>>>(w, wb, wsq);
  gauss_fused_kernel<<<992, 256, 0, stream>>>(x, wb, wsq, out);
}

// Round 10
// 256.139 us; speedup vs baseline: 1.1636x; 1.0727x over previous
//
#include <hip/hip_runtime.h>

typedef unsigned char u8;
typedef float f32x4 __attribute__((ext_vector_type(4)));

#define P_OUT 29791      // 31^3
#define NCH   512

// ---- pack 4 fp32 -> 4 fp8 e4m3 (RNE, OCP) ----
__device__ __forceinline__ unsigned pk4_fp8(float a, float b, float c, float d) {
  int v = __builtin_amdgcn_cvt_pk_fp8_f32(a, b, 0, false);   // low word
  v = __builtin_amdgcn_cvt_pk_fp8_f32(c, d, v, true);        // high word
  return (unsigned)v;
}

// ---- w-prep: 512 rows, 16 rows/block, 32 blocks ----
__global__ void wprep_kernel(const float* __restrict__ w,
                             u8* __restrict__ wb, float* __restrict__ wsq) {
  const int tid = threadIdx.x;
  const int g = blockIdx.x * 16 + (tid >> 4);  // 0..511
  const int c = tid & 15;
  const float4* wr = (const float4*)(w + g * 128 + c * 8);
  float4 f0 = wr[0], f1 = wr[1];
  float s = f0.x*f0.x + f0.y*f0.y + f0.z*f0.z + f0.w*f0.w
          + f1.x*f1.x + f1.y*f1.y + f1.z*f1.z + f1.w*f1.w;
#pragma unroll
  for (int m = 1; m < 16; m <<= 1) s += __shfl_xor(s, m, 64);
  uint2 pk;
  pk.x = pk4_fp8(f0.x, f0.y, f0.z, f0.w);
  pk.y = pk4_fp8(f1.x, f1.y, f1.z, f1.w);
  *(uint2*)(wb + g * 128 + c * 8) = pk;
  if (c == 0) wsq[g] = s;
}

// async global->LDS, 16 B per lane, lands at ldsbase + lane*16
#define GLDS(g, l) __builtin_amdgcn_global_load_lds(                         \
    (const __attribute__((address_space(1))) unsigned int*)(g),              \
    (__attribute__((address_space(3))) unsigned int*)(l), 16, 0, 0)

// lgkm-only barrier: orders LDS ops across waves WITHOUT draining vmcnt,
// so global stores stay fire-and-forget (the r2 lesson). sched_barrier
// stops hipcc hoisting later LDS ops above it (guide rule #18).
#define LGKM_BAR() do {                                                      \
    asm volatile("s_waitcnt lgkmcnt(0)\n\ts_barrier" ::: "memory");          \
    __builtin_amdgcn_sched_barrier(0);                                       \
  } while (0)

// ---- Fused unfold + GEMM + transposed-store epilogue ----
// Identical to the 268.7 us fused-v1 (grid 3968, 256 t, Ws+Xs staging,
// per-lane B pack, 4 ks MFMA) EXCEPT the epilogue: instead of per-lane
// scattered stores (each wave instr = 4 x 64 B segments to 4 ch rows,
// 16 interleaved row-streams per wave -> measured ~2.0 TB/s effective),
// exp results are staged through LDS (reusing dead Ws+Xs as Ep[64][132],
// two ch-passes) and stored ROW-MAJOR: one wave instr = 256 B contiguous
// of ONE ch row, rows sequential -> one write stream per wave, full-line
// L2 merges. Same store instr count, same bytes; contiguity is the only
// variable. XCD-chunked bijective decode: 3968 = 8*496.
__global__ __launch_bounds__(256, 2)
void gauss_fused_kernel(const float* __restrict__ x,
                        const u8* __restrict__ wb,
                        const float* __restrict__ wsq,
                        float* __restrict__ out) {
  __shared__ __align__(16) u8 SMEM[36864];
  u8* Ws = SMEM;                        // w tile [ch][k], 16 KB (phase 1-3)
  float* Xs = (float*)(SMEM + 16384);   // x slab, 20 KB       (phase 1-3)
  float* Ep = (float*)SMEM;             // epilogue [64][132] f32, 33.8 KB

  const int bid = blockIdx.x;
  const int tile = (bid & 7) * 496 + (bid >> 3);   // bijective XCD chunking
  const unsigned nb = (unsigned)tile / 992u;       // 4 batches
  const unsigned rem = (unsigned)tile - nb * 992u;
  const unsigned ct = rem / 248u;                  // 4 ch tiles
  const unsigned r2 = rem - ct * 248u;
  const unsigned d  = r2 >> 3;                     // 31 d values
  const unsigned hb = r2 & 7;                      // 8 h-blocks, fastest
  const int h0 = hb * 4;
  const int nh = (h0 + 4 <= 31) ? 4 : (31 - h0);   // 4 (hb<7) or 3 (hb=7)
  const int nrows = nh * 31;                       // 124 or 93
  const int c0 = ct * 128;
  const int tp0 = d * 961 + h0 * 31;               // tile's base p

  const int tid = threadIdx.x;
  const int wid = tid >> 6;
  const int lane = tid & 63;
  const int quad = lane >> 4;
  const int col = lane & 15;
  const int wch = wid & 1;   // wave ch-half
  const int wp = wid >> 1;   // wave p-half

  // ---- stage W tile: 1024 swizzled chunks (fused-v1 verbatim) ----
#pragma unroll
  for (int t = 0; t < 4; ++t) {
    const int Lb = (wid * 4 + t) * 64;
    const int L = Lb + lane;
    const int row = L >> 3;
    const int jc = (L & 7) ^ (row & 7);
    GLDS(wb + (size_t)(c0 + row) * 128 + jc * 16, &Ws[Lb * 16]);
  }

  // ---- stage x slab [16c][2kd][5hq][32w]: 1280 chunks, 5 rounds ----
#pragma unroll
  for (int t = 0; t < 5; ++t) {
    const int Lb = t * 256 + wid * 64;
    const int L = Lb + lane;
    const int row = L >> 3;                // 0..159
    const int jc = L & 7;
    const unsigned c = (unsigned)row / 10u;
    const unsigned rr = (unsigned)row - c * 10u;
    const unsigned kd = rr / 5u;
    const unsigned hq = rr - kd * 5u;
    const int hg = h0 + (int)hq;
    const int hcl = (hg < 31) ? hg : 31;   // hb=7 tail slot, unused
    GLDS(x + (((size_t)(nb * 16 + c)) << 15) + (d + kd) * 1024 + hcl * 32 + jc * 4,
         &Xs[Lb * 4]);
  }

  // ---- per-lane p-row decode (hides under GLDS flight) ----
  int rb[4];
  int xoff[4];
#pragma unroll
  for (int j = 0; j < 4; ++j) {
    rb[j] = wp * 64 + j * 16 + col;
    const unsigned rc = (unsigned)((rb[j] < nrows) ? rb[j] : (nrows - 1));
    const unsigned hh = rc / 31u;
    const unsigned wv = rc - hh * 31u;
    xoff[j] = (int)(hh * 32 + wv);
  }

  f32x4 acc[4][4];
#pragma unroll
  for (int i = 0; i < 4; ++i)
#pragma unroll
    for (int j = 0; j < 4; ++j) acc[i][j] = (f32x4){0.f, 0.f, 0.f, 0.f};

  float sq[4] = {0.f, 0.f, 0.f, 0.f};

  __syncthreads();   // drains all GLDS (vmcnt)

  // ---- B pack + MFMA (fused-v1 verbatim) ----
  const int c16b = quad >> 1;
  const int hoff = (quad & 1) * 8;
#pragma unroll
  for (int ks = 0; ks < 4; ++ks) {
    long long a[4], b[4];
#pragma unroll
    for (int i = 0; i < 4; ++i) {
      const int rowA = wch * 64 + i * 16 + col;
      const int pa = (ks * 2 + c16b) ^ (rowA & 7);
      a[i] = *(const long long*)&Ws[rowA * 128 + pa * 16 + hoff];
    }
    const int cc = ks * 4 + quad;          // channel for this lane's k-chunk
    const float* xb = &Xs[cc * 320];       // [kd][hq][32] view
#pragma unroll
    for (int j = 0; j < 4; ++j) {
      const float* pB = xb + xoff[j];
      // k-elem order = (kd,kh,kw): strides kd=160, kh=32, kw=1 floats
      const float v0 = pB[0],   v1 = pB[1],   v2 = pB[32],  v3 = pB[33];
      const float v4 = pB[160], v5 = pB[161], v6 = pB[192], v7 = pB[193];
      sq[j] += v0*v0 + v1*v1 + v2*v2 + v3*v3 + v4*v4 + v5*v5 + v6*v6 + v7*v7;
      const unsigned lo = pk4_fp8(v0, v1, v2, v3);
      const unsigned hi = pk4_fp8(v4, v5, v6, v7);
      b[j] = (long long)(((unsigned long long)hi << 32) | lo);
    }
#pragma unroll
    for (int i = 0; i < 4; ++i)
#pragma unroll
      for (int j = 0; j < 4; ++j)
        acc[i][j] = __builtin_amdgcn_mfma_f32_16x16x32_fp8_fp8(a[i], b[j],
                                                               acc[i][j], 0, 0, 0);
  }
  // full ysq per row: reduce partials across the 4 quads
#pragma unroll
  for (int j = 0; j < 4; ++j) {
    sq[j] += __shfl_xor(sq[j], 16, 64);
    sq[j] += __shfl_xor(sq[j], 32, 64);
  }

  LGKM_BAR();   // all waves done with Ws/Xs -> Ep may overwrite SMEM

  // ---- transposed epilogue: 2 passes x {stage exp -> LDS, store rows} ----
  // pass pa covers ch_local = wch*64 + pa*32 + ii*16 + quad*4 + r,
  // Ep row ch2 = wch*32 + ii*16 + quad*4 + r (stride 132: quad pairs
  // {0,2}/{1,3} 2-way on writes = free; reads lane-consecutive = free).
#pragma unroll
  for (int pa = 0; pa < 2; ++pa) {
    // stage: 32 ds_write_b32 per thread
#pragma unroll
    for (int ii = 0; ii < 2; ++ii) {
      const int i = pa * 2 + ii;
#pragma unroll
      for (int r = 0; r < 4; ++r) {
        const int ch2 = wch * 32 + ii * 16 + quad * 4 + r;
        const int chl = wch * 64 + pa * 32 + ii * 16 + quad * 4 + r;
        const float wsv = wsq[c0 + chl];
#pragma unroll
        for (int j = 0; j < 4; ++j)
          Ep[ch2 * 132 + rb[j]] = __expf(2.f * acc[i][j][r] - sq[j] - wsv);
      }
    }
    LGKM_BAR();   // Ep visible to all waves; stores NOT drained

    // store: wave wid owns Ep rows [wid*16, wid*16+16); per row two
    // 256 B contiguous wave-segments (p = lane, p = 64+lane).
#pragma unroll
    for (int rr = 0; rr < 16; ++rr) {
      const int ch2 = wid * 16 + rr;
      const int chl = (ch2 >> 5) * 64 + pa * 32 + (ch2 & 31);
      float* ob = out + ((size_t)(nb * NCH + c0 + chl)) * P_OUT + tp0;
      ob[lane] = Ep[ch2 * 132 + lane];            // 64 <= nrows always
      const int p1 = 64 + lane;
      if (p1 < nrows) ob[p1] = Ep[ch2 * 132 + p1];
    }
    if (pa == 0) LGKM_BAR();   // all waves done reading Ep -> pass 2 may overwrite
  }
}

extern "C" void kernel_launch(void* const* d_in, const int* in_sizes, int n_in,
                              void* d_out, int out_size, void* d_ws, size_t ws_size,
                              hipStream_t stream) {
  const float* x = (const float*)d_in[0];
  const float* w = (const float*)d_in[1];
  float* out = (float*)d_out;
  char* ws = (char*)d_ws;
  // workspace: wb 512*128 fp8 = 65,536 B ; wsq 512*4 = 2,048 B
  u8* wb     = (u8*)ws;
  float* wsq = (float*)(ws + 65536);

  wprep_kernel<<<32, 256, 0, stream>>>(w, wb, wsq);
  gauss_fused_kernel<<<3968, 256, 0, stream>>>(x, wb, wsq, out);
}

// Round 11
// 254.810 us; speedup vs baseline: 1.1696x; 1.0052x over previous
//
#include <hip/hip_runtime.h>

typedef unsigned char u8;
typedef float f32x4 __attribute__((ext_vector_type(4)));
typedef float f4u __attribute__((ext_vector_type(4), aligned(4)));  // dword-aligned float4

#define P_OUT 29791      // 31^3
#define NCH   512

// ---- pack 4 fp32 -> 4 fp8 e4m3 (RNE, OCP) ----
__device__ __forceinline__ unsigned pk4_fp8(float a, float b, float c, float d) {
  int v = __builtin_amdgcn_cvt_pk_fp8_f32(a, b, 0, false);   // low word
  v = __builtin_amdgcn_cvt_pk_fp8_f32(c, d, v, true);        // high word
  return (unsigned)v;
}

// ---- w-prep: 512 rows, 16 rows/block, 32 blocks ----
__global__ void wprep_kernel(const float* __restrict__ w,
                             u8* __restrict__ wb, float* __restrict__ wsq) {
  const int tid = threadIdx.x;
  const int g = blockIdx.x * 16 + (tid >> 4);  // 0..511
  const int c = tid & 15;
  const float4* wr = (const float4*)(w + g * 128 + c * 8);
  float4 f0 = wr[0], f1 = wr[1];
  float s = f0.x*f0.x + f0.y*f0.y + f0.z*f0.z + f0.w*f0.w
          + f1.x*f1.x + f1.y*f1.y + f1.z*f1.z + f1.w*f1.w;
#pragma unroll
  for (int m = 1; m < 16; m <<= 1) s += __shfl_xor(s, m, 64);
  uint2 pk;
  pk.x = pk4_fp8(f0.x, f0.y, f0.z, f0.w);
  pk.y = pk4_fp8(f1.x, f1.y, f1.z, f1.w);
  *(uint2*)(wb + g * 128 + c * 8) = pk;
  if (c == 0) wsq[g] = s;
}

// async global->LDS, 16 B per lane, lands at ldsbase + lane*16
#define GLDS(g, l) __builtin_amdgcn_global_load_lds(                         \
    (const __attribute__((address_space(1))) unsigned int*)(g),              \
    (__attribute__((address_space(3))) unsigned int*)(l), 16, 0, 0)

// lgkm-only barrier: orders LDS ops across waves WITHOUT draining vmcnt,
// so global stores stay fire-and-forget (the r2 lesson). sched_barrier
// stops hipcc hoisting later LDS ops above it (guide rule #18).
#define LGKM_BAR() do {                                                      \
    asm volatile("s_waitcnt lgkmcnt(0)\n\ts_barrier" ::: "memory");          \
    __builtin_amdgcn_sched_barrier(0);                                       \
  } while (0)

// ---- Fused unfold + GEMM + transposed-store epilogue (WIDE stores) ----
// r10 structure verbatim EXCEPT the store sub-phase: Ep rows are read back
// as float4 (16 B/lane, ds_read_b128-aligned) and stored with ONE
// global_store_dwordx4 instruction per 496 B channel strip (31 lanes x
// 16 B = 124 floats exactly); the two wave-halves cover two rows per
// instruction. Store instrs drop 4x (32 -> 8 per wave per pass).
// Addresses are dword-aligned only (tp0 arbitrary mod 4) -> f4u type.
// XCD-chunked bijective decode: 3968 = 8*496.
__global__ __launch_bounds__(256, 2)
void gauss_fused_kernel(const float* __restrict__ x,
                        const u8* __restrict__ wb,
                        const float* __restrict__ wsq,
                        float* __restrict__ out) {
  __shared__ __align__(16) u8 SMEM[36864];
  u8* Ws = SMEM;                        // w tile [ch][k], 16 KB (phase 1-3)
  float* Xs = (float*)(SMEM + 16384);   // x slab, 20 KB       (phase 1-3)
  float* Ep = (float*)SMEM;             // epilogue [64][132] f32, 33.8 KB

  const int bid = blockIdx.x;
  const int tile = (bid & 7) * 496 + (bid >> 3);   // bijective XCD chunking
  const unsigned nb = (unsigned)tile / 992u;       // 4 batches
  const unsigned rem = (unsigned)tile - nb * 992u;
  const unsigned ct = rem / 248u;                  // 4 ch tiles
  const unsigned r2 = rem - ct * 248u;
  const unsigned d  = r2 >> 3;                     // 31 d values
  const unsigned hb = r2 & 7;                      // 8 h-blocks, fastest
  const int h0 = hb * 4;
  const int nh = (h0 + 4 <= 31) ? 4 : (31 - h0);   // 4 (hb<7) or 3 (hb=7)
  const int nrows = nh * 31;                       // 124 or 93
  const int c0 = ct * 128;
  const int tp0 = d * 961 + h0 * 31;               // tile's base p

  const int tid = threadIdx.x;
  const int wid = tid >> 6;
  const int lane = tid & 63;
  const int quad = lane >> 4;
  const int col = lane & 15;
  const int wch = wid & 1;   // wave ch-half
  const int wp = wid >> 1;   // wave p-half

  // ---- stage W tile: 1024 swizzled chunks (fused-v1 verbatim) ----
#pragma unroll
  for (int t = 0; t < 4; ++t) {
    const int Lb = (wid * 4 + t) * 64;
    const int L = Lb + lane;
    const int row = L >> 3;
    const int jc = (L & 7) ^ (row & 7);
    GLDS(wb + (size_t)(c0 + row) * 128 + jc * 16, &Ws[Lb * 16]);
  }

  // ---- stage x slab [16c][2kd][5hq][32w]: 1280 chunks, 5 rounds ----
#pragma unroll
  for (int t = 0; t < 5; ++t) {
    const int Lb = t * 256 + wid * 64;
    const int L = Lb + lane;
    const int row = L >> 3;                // 0..159
    const int jc = L & 7;
    const unsigned c = (unsigned)row / 10u;
    const unsigned rr = (unsigned)row - c * 10u;
    const unsigned kd = rr / 5u;
    const unsigned hq = rr - kd * 5u;
    const int hg = h0 + (int)hq;
    const int hcl = (hg < 31) ? hg : 31;   // hb=7 tail slot, unused
    GLDS(x + (((size_t)(nb * 16 + c)) << 15) + (d + kd) * 1024 + hcl * 32 + jc * 4,
         &Xs[Lb * 4]);
  }

  // ---- per-lane p-row decode (hides under GLDS flight) ----
  int rb[4];
  int xoff[4];
#pragma unroll
  for (int j = 0; j < 4; ++j) {
    rb[j] = wp * 64 + j * 16 + col;
    const unsigned rc = (unsigned)((rb[j] < nrows) ? rb[j] : (nrows - 1));
    const unsigned hh = rc / 31u;
    const unsigned wv = rc - hh * 31u;
    xoff[j] = (int)(hh * 32 + wv);
  }

  f32x4 acc[4][4];
#pragma unroll
  for (int i = 0; i < 4; ++i)
#pragma unroll
    for (int j = 0; j < 4; ++j) acc[i][j] = (f32x4){0.f, 0.f, 0.f, 0.f};

  float sq[4] = {0.f, 0.f, 0.f, 0.f};

  __syncthreads();   // drains all GLDS (vmcnt)

  // ---- B pack + MFMA (fused-v1 verbatim) ----
  const int c16b = quad >> 1;
  const int hoff = (quad & 1) * 8;
#pragma unroll
  for (int ks = 0; ks < 4; ++ks) {
    long long a[4], b[4];
#pragma unroll
    for (int i = 0; i < 4; ++i) {
      const int rowA = wch * 64 + i * 16 + col;
      const int pa = (ks * 2 + c16b) ^ (rowA & 7);
      a[i] = *(const long long*)&Ws[rowA * 128 + pa * 16 + hoff];
    }
    const int cc = ks * 4 + quad;          // channel for this lane's k-chunk
    const float* xb = &Xs[cc * 320];       // [kd][hq][32] view
#pragma unroll
    for (int j = 0; j < 4; ++j) {
      const float* pB = xb + xoff[j];
      // k-elem order = (kd,kh,kw): strides kd=160, kh=32, kw=1 floats
      const float v0 = pB[0],   v1 = pB[1],   v2 = pB[32],  v3 = pB[33];
      const float v4 = pB[160], v5 = pB[161], v6 = pB[192], v7 = pB[193];
      sq[j] += v0*v0 + v1*v1 + v2*v2 + v3*v3 + v4*v4 + v5*v5 + v6*v6 + v7*v7;
      const unsigned lo = pk4_fp8(v0, v1, v2, v3);
      const unsigned hi = pk4_fp8(v4, v5, v6, v7);
      b[j] = (long long)(((unsigned long long)hi << 32) | lo);
    }
#pragma unroll
    for (int i = 0; i < 4; ++i)
#pragma unroll
      for (int j = 0; j < 4; ++j)
        acc[i][j] = __builtin_amdgcn_mfma_f32_16x16x32_fp8_fp8(a[i], b[j],
                                                               acc[i][j], 0, 0, 0);
  }
  // full ysq per row: reduce partials across the 4 quads
#pragma unroll
  for (int j = 0; j < 4; ++j) {
    sq[j] += __shfl_xor(sq[j], 16, 64);
    sq[j] += __shfl_xor(sq[j], 32, 64);
  }

  LGKM_BAR();   // all waves done with Ws/Xs -> Ep may overwrite SMEM

  // ---- transposed epilogue: 2 passes x {stage exp -> LDS, store rows} ----
  const int hw = lane >> 5;          // wave half (row selector)
  const int ll = lane & 31;          // lane within half
  const int nfull = (nrows == 124) ? 31 : 23;   // full-float4 lanes per strip
#pragma unroll
  for (int pa = 0; pa < 2; ++pa) {
    // stage: 32 ds_write_b32 per thread (quad pairs 2-way on banks = free)
#pragma unroll
    for (int ii = 0; ii < 2; ++ii) {
      const int i = pa * 2 + ii;
#pragma unroll
      for (int r = 0; r < 4; ++r) {
        const int ch2 = wch * 32 + ii * 16 + quad * 4 + r;
        const int chl = wch * 64 + pa * 32 + ii * 16 + quad * 4 + r;
        const float wsv = wsq[c0 + chl];
#pragma unroll
        for (int j = 0; j < 4; ++j)
          Ep[ch2 * 132 + rb[j]] = __expf(2.f * acc[i][j][r] - sq[j] - wsv);
      }
    }
    LGKM_BAR();   // Ep visible to all waves; stores NOT drained

    // store: wave wid owns Ep rows [wid*16, wid*16+16); each iteration
    // stores TWO rows (one per wave-half), 16 B/lane dwordx4:
    // one instruction = 2 x 496 B contiguous strips.
#pragma unroll
    for (int rr = 0; rr < 8; ++rr) {
      const int ch2 = wid * 16 + rr * 2 + hw;
      const int chl = (ch2 >> 5) * 64 + pa * 32 + (ch2 & 31);
      float* ob = out + ((size_t)(nb * NCH + c0 + chl)) * P_OUT + tp0;
      if (ll < nfull) {
        const f4u v = *(const f4u*)&Ep[ch2 * 132 + 4 * ll];  // 16B-aligned LDS
        *(f4u*)(ob + 4 * ll) = v;                            // dword-aligned ok
      } else if (ll == 23 && nrows == 93) {
        ob[92] = Ep[ch2 * 132 + 92];                         // 93rd element
      }
    }
    if (pa == 0) LGKM_BAR();   // all waves done reading Ep -> pass 2 overwrite
  }
}

extern "C" void kernel_launch(void* const* d_in, const int* in_sizes, int n_in,
                              void* d_out, int out_size, void* d_ws, size_t ws_size,
                              hipStream_t stream) {
  const float* x = (const float*)d_in[0];
  const float* w = (const float*)d_in[1];
  float* out = (float*)d_out;
  char* ws = (char*)d_ws;
  // workspace: wb 512*128 fp8 = 65,536 B ; wsq 512*4 = 2,048 B
  u8* wb     = (u8*)ws;
  float* wsq = (float*)(ws + 65536);

  wprep_kernel<<<32, 256, 0, stream>>>(w, wb, wsq);
  gauss_fused_kernel<<<3968, 256, 0, stream>>>(x, wb, wsq, out);
}